// Round 8
// baseline (409.336 us; speedup 1.0000x reference)
//
#include <hip/hip_runtime.h>

typedef unsigned short u16;
typedef short bf16x8 __attribute__((ext_vector_type(8)));
typedef float f32x4 __attribute__((ext_vector_type(4)));
typedef unsigned short us8 __attribute__((ext_vector_type(8)));
typedef unsigned short us4 __attribute__((ext_vector_type(4)));
typedef unsigned long long u64;

__device__ __forceinline__ u16 f2bf(float f) {
  unsigned u = __float_as_uint(f);
  u += 0x7fffu + ((u >> 16) & 1u);  // RNE (no NaNs in this workload)
  return (u16)(u >> 16);
}
__device__ __forceinline__ float rlf(float v, int l) {
  return __uint_as_float((unsigned)__builtin_amdgcn_readlane(__float_as_int(v), l));
}

// ---------------------------------------------------------------------------
// Workspace layout (bytes)
// ---------------------------------------------------------------------------
#define OFF_AP   0u           // Apart' f32: 64000x384x4 = 98,304,000
#define OFF_IDX1 98304000u    // 128x500 int
#define OFF_FPSD 98560000u    // fps dist state 128*64*8*4
#define OFF_FPSI 98822144u    // fps fidx state
#define OFF_WB   98824192u    // bf16 weight arena (N x Kp)

// ---------------------------------------------------------------------------
// Fused single-instruction DPP max steps (v_max_f32 with DPP on src0).
// bound_ctrl:0 -> invalid source lanes read 0; fmax(x,0)=x for dist>=0.
// ---------------------------------------------------------------------------
#define DPPMAXF(NAME, MOD)                                              \
  __device__ __forceinline__ float NAME(float v) {                      \
    float r;                                                            \
    asm("v_max_f32 %0, %1, %2 " MOD                                     \
        " row_mask:0xf bank_mask:0xf bound_ctrl:0"                      \
        : "=v"(r) : "v"(v), "v"(v));                                    \
    return r;                                                           \
  }
DPPMAXF(dmx_r1, "row_ror:1")
DPPMAXF(dmx_r2, "row_ror:2")
DPPMAXF(dmx_r4, "row_ror:4")
DPPMAXF(dmx_r8, "row_ror:8")
DPPMAXF(dmx_b15, "row_bcast:15")
DPPMAXF(dmx_b31, "row_bcast:31")

// ---------------------------------------------------------------------------
// FPS. Per iter: dist min-update (exact _rn order); lane-max of 8; per-lane
// winner slot+coords scan vs lane-max (side chain, runs parallel to the DPP
// reduce); 6 fused-DPP wave-max steps -> lane 63; mf=readlane(63);
// ballot(lanemax==mf) -> ffs -> li; coords via 3 parallel readlanes from the
// winner lane's registers (NO LDS read on the critical path).
// Tie-break: smallest lane, then smallest slot (downward scan) = smallest
// point index = np.argmax first-max. Pad slots (>=500) mirror point 0, whose
// lane-0 copy always ties them at a smaller lane -> pads never win.
// ---------------------------------------------------------------------------
__device__ void fps_seg(const float4* cpt, int* out, const int* init1,
                        float* dstate, int* fstate, int b, int t0, int tcnt,
                        int lane) {
  __builtin_amdgcn_s_setprio(3);  // prep: FPS waves co-run with convert blocks
  float px[8], py[8], pz[8], dist[8];
  int base = lane * 8;
#pragma unroll
  for (int j = 0; j < 8; ++j) {
    int p = base + j;
    float4 c = cpt[p < 500 ? p : 0];
    px[j] = c.x; py[j] = c.y; pz[j] = c.z;
  }
  int fidx;
  if (t0 == 0) {
#pragma unroll
    for (int j = 0; j < 8; ++j) dist[j] = 1e10f;
    fidx = init1[b];
  } else {
#pragma unroll
    for (int j = 0; j < 8; ++j) dist[j] = dstate[(b * 64 + lane) * 8 + j];
    fidx = fstate[b];
  }
  float4 c0 = cpt[fidx];
  float cx = c0.x, cy = c0.y, cz = c0.z;

  int hist = 0;
  int tend = t0 + tcnt;  // t0 multiple of 64
  for (int t = t0; t < tend; ++t) {
    hist = (lane == (t & 63)) ? fidx : hist;
    if ((t & 63) == 63) out[(t & ~63) + lane] = hist;  // coalesced wave store
    if (t == 499) break;
#pragma unroll
    for (int j = 0; j < 8; ++j) {
      float dx = __fsub_rn(px[j], cx);
      float dy = __fsub_rn(py[j], cy);
      float dz = __fsub_rn(pz[j], cz);
      float d = __fadd_rn(__fadd_rn(__fmul_rn(dx, dx), __fmul_rn(dy, dy)),
                          __fmul_rn(dz, dz));
      dist[j] = fminf(dist[j], d);
    }
    // lane max of 8 (depth ~3)
    float m01 = fmaxf(dist[0], dist[1]), m23 = fmaxf(dist[2], dist[3]);
    float m45 = fmaxf(dist[4], dist[5]), m67 = fmaxf(dist[6], dist[7]);
    float lm = fmaxf(fmaxf(m01, m23), fmaxf(m45, m67));
    // per-lane winner slot + coords vs lane-max (parallel side chain;
    // downward scan -> smallest slot on tie)
    int sel = 0;
    float sx = px[0], sy = py[0], sz = pz[0];
#pragma unroll
    for (int j = 7; j >= 0; --j) {
      bool hit = (dist[j] == lm);
      sel = hit ? j : sel;
      sx = hit ? px[j] : sx;
      sy = hit ? py[j] : sy;
      sz = hit ? pz[j] : sz;
    }
    // wave max: 6 fused DPP steps, global max reaches lane 63
    float wm = lm;
    wm = dmx_r1(wm);
    wm = dmx_r2(wm);
    wm = dmx_r4(wm);
    wm = dmx_r8(wm);
    wm = dmx_b15(wm);
    wm = dmx_b31(wm);
    float mf = rlf(wm, 63);  // global max -> SGPR
    u64 mask = __ballot(lm == mf);
    int li = (int)__ffsll(mask) - 1;  // smallest lane with lane-max == mf
    cx = rlf(sx, li);
    cy = rlf(sy, li);
    cz = rlf(sz, li);
    fidx = li * 8 + __builtin_amdgcn_readlane(sel, li);  // off critical path
  }
  if ((tend & 63) != 0) {  // partial-group flush (e.g. 448..499)
    int fb = (tend - 1) & ~63;
    if (lane <= ((tend - 1) & 63)) out[fb + lane] = hist;
  }
  if (tend < 500) {
#pragma unroll
    for (int j = 0; j < 8; ++j) dstate[(b * 64 + lane) * 8 + j] = dist[j];
    if (lane == 0) fstate[b] = fidx;
  }
}

// ---------------------------------------------------------------------------
// Fused-MLP building blocks. 512 threads = 8 waves, grid 2(M) x 4(N).
// ---------------------------------------------------------------------------
template <int MI, int NI, int NP, int XC>
__device__ __forceinline__ void gemm_acc(
    f32x4 acc[MI][NI], const u16* __restrict__ aL, int Win, int smask,
    int arow0, const u16* __restrict__ xc, const u16* __restrict__ bb, int Kp,
    int mrow, int quad) {
#pragma unroll
  for (int mi = 0; mi < MI; ++mi)
#pragma unroll
    for (int ni = 0; ni < NI; ++ni) acc[mi][ni] = f32x4{0.f, 0.f, 0.f, 0.f};
#pragma unroll
  for (int kp = 0; kp < NP + XC; ++kp) {
    bf16x8 af[MI];
#pragma unroll
    for (int mi = 0; mi < MI; ++mi) {
      int r = arow0 + mi * 16 + mrow;
      if (XC && kp == NP)
        af[mi] = *(const bf16x8*)(xc + r * 32 + ((quad ^ (r & 3)) << 3));
      else
        af[mi] = *(const bf16x8*)(aL + r * Win +
                                  (((kp * 4 + quad) ^ (r & smask)) << 3));
    }
    bf16x8 bf[NI];
#pragma unroll
    for (int ni = 0; ni < NI; ++ni)
      bf[ni] = *(const bf16x8*)(bb + (size_t)ni * 16 * Kp + kp * 32);
#pragma unroll
    for (int mi = 0; mi < MI; ++mi)
#pragma unroll
      for (int ni = 0; ni < NI; ++ni)
        acc[mi][ni] = __builtin_amdgcn_mfma_f32_16x16x32_bf16(
            af[mi], bf[ni], acc[mi][ni], 0, 0, 0);
  }
}

template <int MI, int NI>
__device__ __forceinline__ void ep_lds(const f32x4 acc[MI][NI], u16* out,
                                       int Wout, const float* __restrict__ bias,
                                       int n0, int arow0, int relu, int mrow,
                                       int quad) {
#pragma unroll
  for (int ni = 0; ni < NI; ++ni) {
    int col = n0 + ni * 16 + mrow;
    float bv = bias[col];
    int seg0 = col >> 3, lo = col & 7;
#pragma unroll
    for (int mi = 0; mi < MI; ++mi)
#pragma unroll
      for (int r = 0; r < 4; ++r) {
        int row = arow0 + mi * 16 + quad * 4 + r;
        float v = acc[mi][ni][r] + bv;
        if (relu) v = fmaxf(v, 0.f);
        out[row * Wout + ((seg0 ^ (row & 7)) << 3) + lo] = f2bf(v);
      }
  }
}

// f32 global epilogue (Apart' = w5a@l6 + b5, no relu)
template <int MI, int NI>
__device__ __forceinline__ void ep_glbf(const f32x4 acc[MI][NI],
                                        float* __restrict__ out, int ldo,
                                        const float* __restrict__ bias, int n0,
                                        long grow0, long rowlim, int mrow,
                                        int quad) {
#pragma unroll
  for (int ni = 0; ni < NI; ++ni) {
    int col = n0 + ni * 16 + mrow;
    float bv = bias[col];
#pragma unroll
    for (int mi = 0; mi < MI; ++mi)
#pragma unroll
      for (int r = 0; r < 4; ++r) {
        long grow = grow0 + mi * 16 + quad * 4 + r;
        if (grow < rowlim)
          out[(size_t)grow * ldo + col] = acc[mi][ni][r] + bv;
      }
  }
}

// ---------------------------------------------------------------------------
// Fused stage A+B(+Apart): 128 rows/block, chain feat->l1->l2->l3->(cat x)->
// l4->l5(LDS)->l6(LDS)->Apart'(f32 global). FPS: 64 blocks x 2 batches
// (waves on separate SIMDs). Dynamic LDS 104KB -> 1 block/CU.
// ---------------------------------------------------------------------------
struct ABArgs {
  const u16 *w1, *w2, *pc1, *w3, *w4, *pc2, *w5;
  const float *b1, *b2, *pc1b, *b3, *b4, *pc2b, *b5;
};

#define AB_LDS_BYTES (98304 + 8192)

__global__ __launch_bounds__(512, 2) void fused_ab(
    ABArgs A, const float* __restrict__ x, const float* __restrict__ cW,
    const float* __restrict__ cb, float* __restrict__ apart,
    const int* __restrict__ init1, int* __restrict__ idx1,
    float* __restrict__ dstate, int* __restrict__ fstate, int t0, int tcnt) {
  extern __shared__ __align__(16) char smem[];
  u16* act = (u16*)smem;             // 128 x up-to-384
  u16* xcat = (u16*)(smem + 98304);  // 128 x 32
  int bid = blockIdx.x, t = threadIdx.x;
  if (bid < 64) {  // FPS: 2 batches per block, waves 0/1 on separate SIMDs
    float4* cpt = (float4*)smem;  // 1000 float4
    const float* xb = x + (size_t)bid * 3000;
    for (int p = t; p < 1000; p += 512)
      cpt[p] = make_float4(xb[p * 3], xb[p * 3 + 1], xb[p * 3 + 2], 0.f);
    __syncthreads();
    int wid = t >> 6;
    if (wid < 2) {
      int b = bid * 2 + wid;
      fps_seg(cpt + wid * 500, idx1 + b * 500, init1, dstate, fstate, b, t0,
              tcnt, t & 63);
    }
    return;
  }
  const int blk = bid - 64;
  const size_t rows0 = (size_t)blk * 128;
  // init: feat (conf,x,y,z) into act[W=32]; x into xcat[W=32]
  if (t < 128) {
    size_t gr = rows0 + t;
    float x0 = x[gr * 3], x1 = x[gr * 3 + 1], x2 = x[gr * 3 + 2];
    float z = x0 * cW[0] + x1 * cW[1] + x2 * cW[2] + cb[0];
    float conf = 1.0f / (1.0f + expf(-z));
    us8 fv;
    fv[0] = f2bf(conf); fv[1] = f2bf(x0); fv[2] = f2bf(x1); fv[3] = f2bf(x2);
    fv[4] = 0; fv[5] = 0; fv[6] = 0; fv[7] = 0;
    *(us8*)(act + t * 32 + ((t & 3) << 3)) = fv;
    us8 xv;
    xv[0] = fv[1]; xv[1] = fv[2]; xv[2] = fv[3];
    xv[3] = 0; xv[4] = 0; xv[5] = 0; xv[6] = 0; xv[7] = 0;
    *(us8*)(xcat + t * 32 + ((t & 3) << 3)) = xv;
  }
  if (t < 384) {  // zero pad segs 1..3 of both 32-wide buffers
    us8 zz = {0, 0, 0, 0, 0, 0, 0, 0};
    int r = t / 3, s = 1 + t % 3;
    *(us8*)(act + r * 32 + ((s ^ (r & 3)) << 3)) = zz;
    *(us8*)(xcat + r * 32 + ((s ^ (r & 3)) << 3)) = zz;
  }
  __syncthreads();
  const int w = t >> 6, lane = t & 63, mrow = lane & 15, quad = lane >> 4;
  const int wm = w >> 2, wn = w & 3;
  const int arow0 = wm * 64;
  {  // L1: feat(K=32) -> 64, relu
    f32x4 acc[4][1];
    const u16* bb = A.w1 + (size_t)(wn * 16 + mrow) * 32 + quad * 8;
    gemm_acc<4, 1, 1, 0>(acc, act, 32, 3, arow0, nullptr, bb, 32, mrow, quad);
    __syncthreads();
    ep_lds<4, 1>(acc, act, 64, A.b1, wn * 16, arow0, 1, mrow, quad);
    __syncthreads();
  }
  {  // L2: 64 -> 256, relu
    f32x4 acc[4][4];
    const u16* bb = A.w2 + (size_t)(wn * 64 + mrow) * 64 + quad * 8;
    gemm_acc<4, 4, 2, 0>(acc, act, 64, 7, arow0, nullptr, bb, 64, mrow, quad);
    __syncthreads();
    ep_lds<4, 4>(acc, act, 256, A.b2, wn * 64, arow0, 1, mrow, quad);
    __syncthreads();
  }
  {  // L3: pc1 256 -> 256, no relu
    f32x4 acc[4][4];
    const u16* bb = A.pc1 + (size_t)(wn * 64 + mrow) * 256 + quad * 8;
    gemm_acc<4, 4, 8, 0>(acc, act, 256, 7, arow0, nullptr, bb, 256, mrow, quad);
    __syncthreads();
    ep_lds<4, 4>(acc, act, 256, A.pc1b, wn * 64, arow0, 0, mrow, quad);
    __syncthreads();
  }
  {  // L4: w3 [l3|x](K=256+32) -> 256, relu
    f32x4 acc[4][4];
    const u16* bb = A.w3 + (size_t)(wn * 64 + mrow) * 288 + quad * 8;
    gemm_acc<4, 4, 8, 1>(acc, act, 256, 7, arow0, xcat, bb, 288, mrow, quad);
    __syncthreads();
    ep_lds<4, 4>(acc, act, 256, A.b3, wn * 64, arow0, 1, mrow, quad);
    __syncthreads();
  }
  {  // L5: w4 256 -> 384, relu, stays in LDS
    f32x4 acc[4][6];
    const u16* bb = A.w4 + (size_t)(wn * 96 + mrow) * 256 + quad * 8;
    gemm_acc<4, 6, 8, 0>(acc, act, 256, 7, arow0, nullptr, bb, 256, mrow, quad);
    __syncthreads();
    ep_lds<4, 6>(acc, act, 384, A.b4, wn * 96, arow0, 1, mrow, quad);
    __syncthreads();
  }
  {  // L6: pc2 384 -> 384, no relu, stays in LDS (bf16, as before)
    f32x4 acc[4][6];
    const u16* bb = A.pc2 + (size_t)(wn * 96 + mrow) * 384 + quad * 8;
    gemm_acc<4, 6, 12, 0>(acc, act, 384, 7, arow0, nullptr, bb, 384, mrow,
                          quad);
    __syncthreads();
    ep_lds<4, 6>(acc, act, 384, A.pc2b, wn * 96, arow0, 0, mrow, quad);
    __syncthreads();
  }
  {  // Apart' = w5a(384x384) @ l6 + b5 -> f32 global (FPS-independent!)
    f32x4 acc[4][6];
    const u16* bb = A.w5 + (size_t)(wn * 96 + mrow) * 416 + quad * 8;
    gemm_acc<4, 6, 12, 0>(acc, act, 384, 7, arow0, nullptr, bb, 416, mrow,
                          quad);
    ep_glbf<4, 6>(acc, apart, 384, A.b5, wn * 96, (long)(rows0 + arow0), 64000,
                  mrow, quad);
  }
}

// ---------------------------------------------------------------------------
// Fused stage C: 4 blocks/batch x 128 rows. Gather Apart'[b*500+idx1[p]]
// (f32) + w5b·x[p] -> relu -> bf16 l7 (LDS) -> l8 GEMM -> per-batch col max.
// Dynamic LDS: l7 96KB + w5b 6KB + red 2KB -> 1 block/CU.
// ---------------------------------------------------------------------------
#define C_LDS_BYTES (98304 + 6144 + 2048)

__global__ __launch_bounds__(512, 2) void fused_c(
    const u16* __restrict__ w6b, const float* __restrict__ b6,
    const float* __restrict__ x, const float* __restrict__ apart,
    const float* __restrict__ w5src, float* __restrict__ outf,
    const int* __restrict__ idx1) {
  extern __shared__ __align__(16) char smem[];
  u16* l7 = (u16*)smem;                        // 128 x 384, swizzled
  float* xw = (float*)(smem + 98304);          // [384][4]: w5b cols 0..2
  float* red = (float*)(smem + 98304 + 6144);  // 2 x 256
  int bid = blockIdx.x, t = threadIdx.x;
  const int b = bid >> 2, q = bid & 3;
  const int prow0 = q * 128;
  if (t < 384) {
    xw[t * 4 + 0] = w5src[(size_t)t * 387 + 384];
    xw[t * 4 + 1] = w5src[(size_t)t * 387 + 385];
    xw[t * 4 + 2] = w5src[(size_t)t * 387 + 386];
    xw[t * 4 + 3] = 0.f;
  }
  __syncthreads();
  {  // gather + Bpart + relu + bf16 -> l7 LDS (4 threads per row)
    int row = t >> 2;
    int p = prow0 + row, pe = p < 500 ? p : 0;
    int s = idx1[b * 500 + pe];
    const float* ap = apart + ((size_t)b * 500 + (size_t)s) * 384;
    const float* xp = x + ((size_t)b * 500 + pe) * 3;
    float x0 = xp[0], x1 = xp[1], x2 = xp[2];
#pragma unroll
    for (int it = 0; it < 24; ++it) {
      int c = (t & 3) * 4 + it * 16;
      float4 a4 = *(const float4*)(ap + c);
      const float4* wv = (const float4*)(xw + c * 4);
      float v0 = fmaxf(a4.x + wv[0].x * x0 + wv[0].y * x1 + wv[0].z * x2, 0.f);
      float v1 = fmaxf(a4.y + wv[1].x * x0 + wv[1].y * x1 + wv[1].z * x2, 0.f);
      float v2 = fmaxf(a4.z + wv[2].x * x0 + wv[2].y * x1 + wv[2].z * x2, 0.f);
      float v3 = fmaxf(a4.w + wv[3].x * x0 + wv[3].y * x1 + wv[3].z * x2, 0.f);
      us4 pk;
      pk[0] = f2bf(v0); pk[1] = f2bf(v1); pk[2] = f2bf(v2); pk[3] = f2bf(v3);
      int seg = c >> 3, half = (c >> 2) & 1;
      *(us4*)(l7 + row * 384 + ((seg ^ (row & 7)) << 3) + half * 4) = pk;
    }
  }
  __syncthreads();
  const int w = t >> 6, lane = t & 63, mrow = lane & 15, quad = lane >> 4;
  const int wm = w >> 2, wn = w & 3;
  const int arow0 = wm * 64;
  {  // L8: w6 384 -> 512 (A from l7 LDS), relu + per-batch col max
#pragma unroll
    for (int ph = 0; ph < 2; ++ph) {
      f32x4 acc[4][4];
      int n0 = ph * 256 + wn * 64;
      const u16* bb = w6b + (size_t)(n0 + mrow) * 384 + quad * 8;
      gemm_acc<4, 4, 12, 0>(acc, l7, 384, 7, arow0, nullptr, bb, 384, mrow,
                            quad);
#pragma unroll
      for (int ni = 0; ni < 4; ++ni) {
        int cc = n0 + ni * 16 + mrow;
        float bv = b6[cc];
        float mx = 0.f;
#pragma unroll
        for (int mi = 0; mi < 4; ++mi)
#pragma unroll
          for (int r = 0; r < 4; ++r) {
            int p = prow0 + arow0 + mi * 16 + quad * 4 + r;
            float v = fmaxf(acc[mi][ni][r] + bv, 0.f);
            if (p < 500) mx = fmaxf(mx, v);
          }
        mx = fmaxf(mx, __shfl_xor(mx, 16, 64));
        mx = fmaxf(mx, __shfl_xor(mx, 32, 64));
        if (quad == 0) red[wm * 256 + wn * 64 + ni * 16 + mrow] = mx;
      }
      __syncthreads();
      if (t < 256) {
        float m = fmaxf(red[t], red[256 + t]);
        atomicMax((unsigned*)&outf[(size_t)b * 512 + ph * 256 + t],
                  __float_as_uint(m));
      }
      __syncthreads();
    }
  }
}

// ---------------------------------------------------------------------------
// prep: weight convert (N x Kp, k-pad zeros) + outf zero + FPS segment 0
// (64 blocks x 2 batches)
// ---------------------------------------------------------------------------
struct PrepArgs {
  const float* wsrc[8];
  u16* wdst[8];
  int wN[8], wK[8], wKp[8];
  int wstart[9];
};

__global__ __launch_bounds__(256) void prep_kernel(
    PrepArgs pa, const float* __restrict__ x, float* __restrict__ outf,
    const int* __restrict__ init1, int* __restrict__ idx1,
    float* __restrict__ dstate, int* __restrict__ fstate, int tcnt) {
  __shared__ float4 cpt[1000];
  int bid = blockIdx.x, t = threadIdx.x;
  if (bid < 64) {
    const float* xb = x + (size_t)bid * 3000;
    for (int p = t; p < 1000; p += 256)
      cpt[p] = make_float4(xb[p * 3], xb[p * 3 + 1], xb[p * 3 + 2], 0.f);
    __syncthreads();
    int wid = t >> 6;
    if (wid < 2) {
      int b = bid * 2 + wid;
      fps_seg(cpt + wid * 500, idx1 + b * 500, init1, dstate, fstate, b, 0,
              tcnt, t & 63);
    }
    return;
  }
  int i = (bid - 64) * 256 + t;
  int S = pa.wstart[8];
  if (i < S) {
    int wsel = 0;
#pragma unroll
    for (int j = 1; j < 8; ++j)
      if (i >= pa.wstart[j]) wsel = j;
    int local = i - pa.wstart[wsel];
    int Kp = pa.wKp[wsel];
    int n = local / Kp, k = local - n * Kp;
    pa.wdst[wsel][local] =
        (k < pa.wK[wsel]) ? f2bf(pa.wsrc[wsel][n * pa.wK[wsel] + k]) : (u16)0;
  } else if (i < S + 65536) {
    outf[i - S] = 0.f;
  }
}

// ---------------------------------------------------------------------------
extern "C" void kernel_launch(void* const* d_in, const int* in_sizes, int n_in,
                              void* d_out, int out_size, void* d_ws,
                              size_t ws_size, hipStream_t stream) {
  const float* x      = (const float*)d_in[0];
  const float* conf_W = (const float*)d_in[1];
  const float* conf_b = (const float*)d_in[2];
  const float* w1     = (const float*)d_in[3];
  const float* b1     = (const float*)d_in[4];
  const float* w2     = (const float*)d_in[5];
  const float* b2     = (const float*)d_in[6];
  const float* pc1_W  = (const float*)d_in[7];
  const float* pc1_b  = (const float*)d_in[8];
  const float* w3     = (const float*)d_in[9];
  const float* b3     = (const float*)d_in[10];
  const float* w4     = (const float*)d_in[11];
  const float* b4     = (const float*)d_in[12];
  const float* pc2_W  = (const float*)d_in[13];
  const float* pc2_b  = (const float*)d_in[14];
  const float* w5     = (const float*)d_in[15];
  const float* b5     = (const float*)d_in[16];
  const float* w6     = (const float*)d_in[17];
  const float* b6     = (const float*)d_in[18];
  const int* init1    = (const int*)d_in[20];

  char* ws = (char*)d_ws;
  float* apart = (float*)(ws + OFF_AP);
  int* idx1 = (int*)(ws + OFF_IDX1);
  float* dstate = (float*)(ws + OFF_FPSD);
  int* fstate = (int*)(ws + OFF_FPSI);
  u16* wb = (u16*)(ws + OFF_WB);
  float* outf = (float*)d_out;

  PrepArgs pa;
  const float* srcs[8] = {w1, w2, pc1_W, w3, w4, pc2_W, w5, w6};
  int Ns[8]  = {64, 256, 256, 256, 384, 384, 384, 512};
  int Ks[8]  = {4, 64, 256, 259, 256, 384, 387, 384};
  int Kps[8] = {32, 64, 256, 288, 256, 384, 416, 384};
  u16* WBp[8];
  int cum = 0;
  for (int i = 0; i < 8; ++i) {
    pa.wsrc[i] = srcs[i];
    pa.wdst[i] = WBp[i] = wb + cum;
    pa.wN[i] = Ns[i];
    pa.wK[i] = Ks[i];
    pa.wKp[i] = Kps[i];
    pa.wstart[i] = cum;
    cum += Ns[i] * Kps[i];
  }
  pa.wstart[8] = cum;
  int total = cum + 65536;

  // D1: weights + outf zero + FPS iters [0,64)
  prep_kernel<<<64 + (total + 255) / 256, 256, 0, stream>>>(
      pa, x, outf, init1, idx1, dstate, fstate, 64);

  // D2: fused A+B+Apart (500 MLP blocks) + FPS iters [64,500) in 64 blocks
  ABArgs A;
  A.w1 = WBp[0]; A.w2 = WBp[1]; A.pc1 = WBp[2];
  A.w3 = WBp[3]; A.w4 = WBp[4]; A.pc2 = WBp[5]; A.w5 = WBp[6];
  A.b1 = b1; A.b2 = b2; A.pc1b = pc1_b; A.b3 = b3; A.b4 = b4;
  A.pc2b = pc2_b; A.b5 = b5;
  fused_ab<<<64 + 500, 512, AB_LDS_BYTES, stream>>>(
      A, x, conf_W, conf_b, apart, init1, idx1, dstate, fstate, 64, 436);

  // D3: fused C (gather Apart' + Bpart + l8 + max), 128 rows/block
  fused_c<<<512, 512, C_LDS_BYTES, stream>>>(WBp[7], b6, x, apart, w5, outf,
                                             idx1);
}